// Round 1
// baseline (3115.983 us; speedup 1.0000x reference)
//
#include <hip/hip_runtime.h>
#include <hip/hip_bf16.h>
#include <cstdint>
#include <cstddef>

#define D 128
#define NNODES 200000
#define NEDGES 500000
#define NLAYERS 5
#define BN_EPS 1e-5f
#define MAXDEG 32

// ---------------- CSR build ----------------
__global__ void k_zero(int* __restrict__ p, int n) {
    int i = blockIdx.x * 256 + threadIdx.x;
    if (i < n) p[i] = 0;
}

__global__ void k_fill_edges(const int* __restrict__ ei, int* __restrict__ deg,
                             int* __restrict__ elist, int n_edges) {
    int e = blockIdx.x * 256 + threadIdx.x;
    if (e >= n_edges) return;
    int dst = ei[n_edges + e];          // edge_index[1][e]
    int pos = atomicAdd(&deg[dst], 1);
    if (pos < MAXDEG) elist[dst * MAXDEG + pos] = e;
}

// ---------------- atom encoder layer 1: x[N,12]@W1[12,128] + BN + ReLU ----------------
__global__ void k_ae1(const float* __restrict__ x, const float* __restrict__ W,
                      const float* __restrict__ b, const float* __restrict__ g,
                      const float* __restrict__ be, const float* __restrict__ m,
                      const float* __restrict__ v, float* __restrict__ out) {
    __shared__ float sW[12 * 128];
    int tid = threadIdx.x;
    for (int i = tid; i < 12 * 128; i += 256) sW[i] = W[i];
    __syncthreads();
    int f = tid & 127;
    int n = blockIdx.x * 2 + (tid >> 7);
    if (n >= NNODES) return;
    const float* xr = x + (size_t)n * 12;
    float acc = b[f];
#pragma unroll
    for (int k = 0; k < 12; ++k) acc += xr[k] * sW[k * 128 + f];
    float sc = g[f] * rsqrtf(v[f] + BN_EPS);
    acc = (acc - m[f]) * sc + be[f];
    out[(size_t)n * D + f] = fmaxf(acc, 0.f);
}

// ---------------- generic Linear(D,D) + optional BN + optional ReLU ----------------
// tile: 64 nodes x 64 feats per block, 256 threads, 4x4 register tile each
__launch_bounds__(256, 2)
__global__ void k_lin(const float* __restrict__ in, const float* __restrict__ W,
                      const float* __restrict__ bias,
                      const float* __restrict__ g, const float* __restrict__ be,
                      const float* __restrict__ m, const float* __restrict__ v,
                      float* __restrict__ out, int do_bn, int do_relu) {
    __shared__ float sIn[128][68];   // [k][node], transposed input tile
    __shared__ float sW[128][68];    // [k][feat] slice
    int tid = threadIdx.x;
    int nb = blockIdx.x * 64;
    int fb = blockIdx.y * 64;

    // stage input tile (64 nodes x 128 k), transposed
    {
        const float4* inv = (const float4*)(in + (size_t)nb * D);
#pragma unroll
        for (int it = 0; it < 8; ++it) {
            int s = tid + it * 256;          // 0..2047
            int n = s >> 5, kq = s & 31;
            float4 val = inv[n * 32 + kq];
            int k = kq * 4;
            sIn[k][n] = val.x; sIn[k + 1][n] = val.y;
            sIn[k + 2][n] = val.z; sIn[k + 3][n] = val.w;
        }
#pragma unroll
        for (int it = 0; it < 8; ++it) {
            int s = tid + it * 256;          // 0..2047
            int k = s >> 4, fq = s & 15;
            float4 val = *(const float4*)(W + (size_t)k * D + fb + fq * 4);
            *(float4*)&sW[k][fq * 4] = val;
        }
    }
    __syncthreads();

    int tx = tid & 15;       // feat group
    int ty = tid >> 4;       // node group
    float acc[4][4] = {};
#pragma unroll 4
    for (int k = 0; k < 128; ++k) {
        float4 a = *(float4*)&sIn[k][ty * 4];
        float4 w = *(float4*)&sW[k][tx * 4];
        acc[0][0] += a.x * w.x; acc[0][1] += a.x * w.y; acc[0][2] += a.x * w.z; acc[0][3] += a.x * w.w;
        acc[1][0] += a.y * w.x; acc[1][1] += a.y * w.y; acc[1][2] += a.y * w.z; acc[1][3] += a.y * w.w;
        acc[2][0] += a.z * w.x; acc[2][1] += a.z * w.y; acc[2][2] += a.z * w.z; acc[2][3] += a.z * w.w;
        acc[3][0] += a.w * w.x; acc[3][1] += a.w * w.y; acc[3][2] += a.w * w.z; acc[3][3] += a.w * w.w;
    }

    // epilogue: res = (acc + bias)*sc + sh ; sc=g*rsqrt(v+eps), sh=be-m*sc (identity if !do_bn)
    int f0 = fb + tx * 4;
    float4 bb = *(const float4*)(bias + f0);
    float scx = 1.f, scy = 1.f, scz = 1.f, scw = 1.f;
    float shx = 0.f, shy = 0.f, shz = 0.f, shw = 0.f;
    if (do_bn) {
        float4 gg = *(const float4*)(g + f0);
        float4 bee = *(const float4*)(be + f0);
        float4 mm = *(const float4*)(m + f0);
        float4 vv = *(const float4*)(v + f0);
        scx = gg.x * rsqrtf(vv.x + BN_EPS); shx = bee.x - mm.x * scx;
        scy = gg.y * rsqrtf(vv.y + BN_EPS); shy = bee.y - mm.y * scy;
        scz = gg.z * rsqrtf(vv.z + BN_EPS); shz = bee.z - mm.z * scz;
        scw = gg.w * rsqrtf(vv.w + BN_EPS); shw = bee.w - mm.w * scw;
    }
#pragma unroll
    for (int i = 0; i < 4; ++i) {
        float4 r;
        r.x = (acc[i][0] + bb.x) * scx + shx;
        r.y = (acc[i][1] + bb.y) * scy + shy;
        r.z = (acc[i][2] + bb.z) * scz + shz;
        r.w = (acc[i][3] + bb.w) * scw + shw;
        if (do_relu) {
            r.x = fmaxf(r.x, 0.f); r.y = fmaxf(r.y, 0.f);
            r.z = fmaxf(r.z, 0.f); r.w = fmaxf(r.w, 0.f);
        }
        *(float4*)(out + (size_t)(nb + ty * 4 + i) * D + f0) = r;
    }
}

// ---------------- GIN aggregate: z_pre = (1+eps)*h + sum_in relu(h[src]+e_emb) ----------------
__global__ void k_agg(const float* __restrict__ h, const int* __restrict__ ei,
                      const int* __restrict__ ea, const float* __restrict__ bond,
                      const float* __restrict__ eps_arr, int layer,
                      const int* __restrict__ deg, const int* __restrict__ elist,
                      float* __restrict__ out) {
    __shared__ float sB[3 * 8 * 128];
    int tid = threadIdx.x;
    const float* bl = bond + (size_t)layer * 3 * 8 * 128;
    for (int i = tid; i < 3 * 8 * 128; i += 256) sB[i] = bl[i];
    __syncthreads();
    int f = tid & 127;
    int n = blockIdx.x * 2 + (tid >> 7);
    if (n >= NNODES) return;
    float epsv = eps_arr[layer];
    float acc = (1.f + epsv) * h[(size_t)n * D + f];
    int dgr = min(deg[n], MAXDEG);
    for (int i = 0; i < dgr; ++i) {
        int e = elist[n * MAXDEG + i];
        int s = ei[e];                       // edge_index[0][e] = src
        int a0 = ea[e * 3], a1 = ea[e * 3 + 1], a2 = ea[e * 3 + 2];
        float msg = h[(size_t)s * D + f] + sB[a0 * D + f] + sB[(8 + a1) * D + f] + sB[(16 + a2) * D + f];
        acc += fmaxf(msg, 0.f);
    }
    out[(size_t)n * D + f] = acc;
}

// ---------------- launch ----------------
extern "C" void kernel_launch(void* const* d_in, const int* in_sizes, int n_in,
                              void* d_out, int out_size, void* d_ws, size_t ws_size,
                              hipStream_t stream) {
    const float* x      = (const float*)d_in[0];
    const int*   ei     = (const int*)d_in[1];
    const int*   ea     = (const int*)d_in[2];
    const float* aeW1   = (const float*)d_in[3];
    const float* aeb1   = (const float*)d_in[4];
    const float* aeg1   = (const float*)d_in[5];
    const float* aebe1  = (const float*)d_in[6];
    const float* aem1   = (const float*)d_in[7];
    const float* aev1   = (const float*)d_in[8];
    const float* aeW2   = (const float*)d_in[9];
    const float* aeb2   = (const float*)d_in[10];
    const float* aeg2   = (const float*)d_in[11];
    const float* aebe2  = (const float*)d_in[12];
    const float* aem2   = (const float*)d_in[13];
    const float* aev2   = (const float*)d_in[14];
    const float* aeW3   = (const float*)d_in[15];
    const float* aeb3   = (const float*)d_in[16];
    const float* bond   = (const float*)d_in[17];
    const float* eps    = (const float*)d_in[18];
    const float* mlpW1  = (const float*)d_in[19];
    const float* mlpb1  = (const float*)d_in[20];
    const float* mlpg   = (const float*)d_in[21];
    const float* mlpbe  = (const float*)d_in[22];
    const float* mlpm   = (const float*)d_in[23];
    const float* mlpv   = (const float*)d_in[24];
    const float* mlpW2  = (const float*)d_in[25];
    const float* mlpb2  = (const float*)d_in[26];
    const float* outg   = (const float*)d_in[27];
    const float* outbe  = (const float*)d_in[28];
    const float* outm   = (const float*)d_in[29];
    const float* outv   = (const float*)d_in[30];

    float* bufB = (float*)d_out;                       // N*D fp32 (also final output)
    char*  ws   = (char*)d_ws;
    float* bufA = (float*)ws;                          // N*D fp32 = 102,400,000 B
    int*   deg  = (int*)(ws + 102400000);              // N ints
    int*   elist= (int*)(ws + 103200000);              // N*MAXDEG ints

    // CSR build (per launch; graph is static within a launch, reused for all 5 layers)
    k_zero<<<(NNODES + 255) / 256, 256, 0, stream>>>(deg, NNODES);
    k_fill_edges<<<(NEDGES + 255) / 256, 256, 0, stream>>>(ei, deg, elist, NEDGES);

    // atom encoder
    k_ae1<<<NNODES / 2, 256, 0, stream>>>(x, aeW1, aeb1, aeg1, aebe1, aem1, aev1, bufA);
    dim3 gg(NNODES / 64, 2);
    k_lin<<<gg, 256, 0, stream>>>(bufA, aeW2, aeb2, aeg2, aebe2, aem2, aev2, bufB, 1, 1);
    k_lin<<<gg, 256, 0, stream>>>(bufB, aeW3, aeb3, nullptr, nullptr, nullptr, nullptr, bufA, 0, 0);

    // GIN layers; h starts in bufA. Parity lands layer-4 output in bufB == d_out.
    float* hcur = bufA;
    float* hoth = bufB;
    for (int l = 0; l < NLAYERS; ++l) {
        k_agg<<<NNODES / 2, 256, 0, stream>>>(hcur, ei, ea, bond, eps, l, deg, elist, hoth);
        k_lin<<<gg, 256, 0, stream>>>(hoth, mlpW1 + (size_t)l * D * D, mlpb1 + (size_t)l * D,
                                      mlpg + (size_t)l * D, mlpbe + (size_t)l * D,
                                      mlpm + (size_t)l * D, mlpv + (size_t)l * D, hcur, 1, 1);
        k_lin<<<gg, 256, 0, stream>>>(hcur, mlpW2 + (size_t)l * D * D, mlpb2 + (size_t)l * D,
                                      outg + (size_t)l * D, outbe + (size_t)l * D,
                                      outm + (size_t)l * D, outv + (size_t)l * D, hoth,
                                      1, (l < NLAYERS - 1) ? 1 : 0);
        float* t = hcur; hcur = hoth; hoth = t;
    }
    (void)in_sizes; (void)n_in; (void)out_size; (void)ws_size;
}

// Round 2
// 1750.351 us; speedup vs baseline: 1.7802x; 1.7802x over previous
//
#include <hip/hip_runtime.h>
#include <hip/hip_bf16.h>
#include <cstdint>
#include <cstddef>

#define D 128
#define NNODES 200000
#define NEDGES 500000
#define NLAYERS 5
#define BN_EPS 1e-5f
#define MAXDEG 32

// ---------------- CSR build ----------------
__global__ void k_zero(int* __restrict__ p, int n) {
    int i = blockIdx.x * 256 + threadIdx.x;
    if (i < n) p[i] = 0;
}

// pack src (18 bits) + a0,a1,a2 (3 bits each) into one int per edge
__global__ void k_fill_edges(const int* __restrict__ ei, const int* __restrict__ ea,
                             int* __restrict__ deg, int* __restrict__ elist, int n_edges) {
    int e = blockIdx.x * 256 + threadIdx.x;
    if (e >= n_edges) return;
    int dst = ei[n_edges + e];          // edge_index[1][e]
    int src = ei[e];                    // edge_index[0][e]
    int a0 = ea[e * 3], a1 = ea[e * 3 + 1], a2 = ea[e * 3 + 2];
    int rec = src | (a0 << 18) | (a1 << 21) | (a2 << 24);
    int pos = atomicAdd(&deg[dst], 1);
    if (pos < MAXDEG) elist[dst * MAXDEG + pos] = rec;
}

// ---------------- atom encoder layer 1: x[N,12]@W1[12,128] + BN + ReLU ----------------
__global__ void k_ae1(const float* __restrict__ x, const float* __restrict__ W,
                      const float* __restrict__ b, const float* __restrict__ g,
                      const float* __restrict__ be, const float* __restrict__ m,
                      const float* __restrict__ v, float* __restrict__ out) {
    __shared__ float sW[12 * 128];
    int tid = threadIdx.x;
    for (int i = tid; i < 12 * 128; i += 256) sW[i] = W[i];
    __syncthreads();
    int f = tid & 127;
    int n = blockIdx.x * 2 + (tid >> 7);
    if (n >= NNODES) return;
    const float* xr = x + (size_t)n * 12;
    float acc = b[f];
#pragma unroll
    for (int k = 0; k < 12; ++k) acc += xr[k] * sW[k * 128 + f];
    float sc = g[f] * rsqrtf(v[f] + BN_EPS);
    acc = (acc - m[f]) * sc + be[f];
    out[(size_t)n * D + f] = fmaxf(acc, 0.f);
}

// ---------------- Linear(128,128) + optional BN + optional ReLU ----------------
// tile: 64 nodes x 128 feats per block, 256 threads, each 4 nodes x 8 feats,
// k chunked by 64. LDS 51.2KB -> 3 blocks/CU.
__launch_bounds__(256, 3)
__global__ void k_lin(const float* __restrict__ in, const float* __restrict__ W,
                      const float* __restrict__ bias,
                      const float* __restrict__ g, const float* __restrict__ be,
                      const float* __restrict__ m, const float* __restrict__ v,
                      float* __restrict__ out, int do_bn, int do_relu) {
    __shared__ float sIn[64][68];    // [k][node] transposed chunk
    __shared__ float sW[64][132];    // [k][feat] chunk (row = 132 floats = 16B-mult)
    int tid = threadIdx.x;
    size_t nb = (size_t)blockIdx.x * 64;
    int tx = tid & 15;   // feat group: 8 feats at tx*8
    int ty = tid >> 4;   // node group: 4 nodes at ty*4
    float acc[4][8] = {};

#pragma unroll
    for (int c = 0; c < 2; ++c) {
        int k0 = c * 64;
        // stage input chunk: 64 nodes x 64 k, transposed
#pragma unroll
        for (int it = 0; it < 4; ++it) {
            int s = tid + it * 256;          // 0..1023
            int n = s >> 4, kq = s & 15;
            float4 val = *(const float4*)(in + (nb + n) * D + k0 + kq * 4);
            sIn[kq * 4 + 0][n] = val.x; sIn[kq * 4 + 1][n] = val.y;
            sIn[kq * 4 + 2][n] = val.z; sIn[kq * 4 + 3][n] = val.w;
        }
        // stage W chunk: 64 k x 128 f
#pragma unroll
        for (int it = 0; it < 8; ++it) {
            int s = tid + it * 256;          // 0..2047
            int k = s >> 5, fq = s & 31;
            *(float4*)&sW[k][fq * 4] = *(const float4*)(W + (size_t)(k0 + k) * D + fq * 4);
        }
        __syncthreads();
#pragma unroll 8
        for (int k = 0; k < 64; ++k) {
            float4 a  = *(float4*)&sIn[k][ty * 4];
            float4 w0 = *(float4*)&sW[k][tx * 8];
            float4 w1 = *(float4*)&sW[k][tx * 8 + 4];
            float av[4] = {a.x, a.y, a.z, a.w};
            float wv[8] = {w0.x, w0.y, w0.z, w0.w, w1.x, w1.y, w1.z, w1.w};
#pragma unroll
            for (int j = 0; j < 8; ++j) {
#pragma unroll
                for (int i = 0; i < 4; ++i) acc[i][j] += av[i] * wv[j];
            }
        }
        __syncthreads();
    }

    // epilogue: (acc + bias)*sc + sh, optional relu
    int f0 = tx * 8;
    float bv[8], sc[8], sh[8];
    {
        float4 b0 = *(const float4*)(bias + f0);
        float4 b1 = *(const float4*)(bias + f0 + 4);
        bv[0]=b0.x; bv[1]=b0.y; bv[2]=b0.z; bv[3]=b0.w;
        bv[4]=b1.x; bv[5]=b1.y; bv[6]=b1.z; bv[7]=b1.w;
    }
    if (do_bn) {
        float4 g0 = *(const float4*)(g + f0),  g1 = *(const float4*)(g + f0 + 4);
        float4 e0 = *(const float4*)(be + f0), e1 = *(const float4*)(be + f0 + 4);
        float4 m0 = *(const float4*)(m + f0),  m1 = *(const float4*)(m + f0 + 4);
        float4 v0 = *(const float4*)(v + f0),  v1 = *(const float4*)(v + f0 + 4);
        float gg[8] = {g0.x,g0.y,g0.z,g0.w,g1.x,g1.y,g1.z,g1.w};
        float ee[8] = {e0.x,e0.y,e0.z,e0.w,e1.x,e1.y,e1.z,e1.w};
        float mm[8] = {m0.x,m0.y,m0.z,m0.w,m1.x,m1.y,m1.z,m1.w};
        float vv[8] = {v0.x,v0.y,v0.z,v0.w,v1.x,v1.y,v1.z,v1.w};
#pragma unroll
        for (int j = 0; j < 8; ++j) { sc[j] = gg[j] * rsqrtf(vv[j] + BN_EPS); sh[j] = ee[j] - mm[j] * sc[j]; }
    } else {
#pragma unroll
        for (int j = 0; j < 8; ++j) { sc[j] = 1.f; sh[j] = 0.f; }
    }
#pragma unroll
    for (int i = 0; i < 4; ++i) {
        float o[8];
#pragma unroll
        for (int j = 0; j < 8; ++j) {
            float r = (acc[i][j] + bv[j]) * sc[j] + sh[j];
            o[j] = do_relu ? fmaxf(r, 0.f) : r;
        }
        float* op = out + (nb + ty * 4 + i) * D + f0;
        *(float4*)op       = make_float4(o[0], o[1], o[2], o[3]);
        *(float4*)(op + 4) = make_float4(o[4], o[5], o[6], o[7]);
    }
}

// ---------------- GIN aggregate: z = (1+eps)*h + sum_in relu(h[src]+e_emb) ----------------
// 8 nodes/block, 32 float4-lanes per node, packed edge recs, 4-deep gather prefetch.
__global__ void k_agg(const float4* __restrict__ h4, const float* __restrict__ bond,
                      const float* __restrict__ eps_arr, int layer,
                      const int* __restrict__ deg, const int* __restrict__ elist,
                      float4* __restrict__ out4) {
    __shared__ float4 sB[24 * 32];   // 3 tables x 8 vals x 32 float4
    int tid = threadIdx.x;
    const float4* bl = (const float4*)(bond + (size_t)layer * 3 * 8 * 128);
    for (int i = tid; i < 24 * 32; i += 256) sB[i] = bl[i];
    __syncthreads();
    int f4 = tid & 31;
    int n = blockIdx.x * 8 + (tid >> 5);
    float epsv = 1.f + eps_arr[layer];
    float4 hs = h4[(size_t)n * 32 + f4];
    float4 acc = make_float4(epsv * hs.x, epsv * hs.y, epsv * hs.z, epsv * hs.w);
    int dgr = min(deg[n], MAXDEG);
    int recv = elist[(size_t)n * MAXDEG + f4];   // whole row, coalesced
    for (int base = 0; base < dgr; base += 4) {
        float4 hv[4]; int rr[4];
#pragma unroll
        for (int j = 0; j < 4; ++j) {
            rr[j] = __shfl(recv, base + j, 32);
            if (base + j < dgr) hv[j] = h4[(size_t)(rr[j] & 0x3FFFF) * 32 + f4];
        }
#pragma unroll
        for (int j = 0; j < 4; ++j) {
            if (base + j < dgr) {
                int r = rr[j];
                float4 b0 = sB[((r >> 18) & 7) * 32 + f4];
                float4 b1 = sB[(8 + ((r >> 21) & 7)) * 32 + f4];
                float4 b2 = sB[(16 + ((r >> 24) & 7)) * 32 + f4];
                float mx = hv[j].x + b0.x + b1.x + b2.x;
                float my = hv[j].y + b0.y + b1.y + b2.y;
                float mz = hv[j].z + b0.z + b1.z + b2.z;
                float mw = hv[j].w + b0.w + b1.w + b2.w;
                acc.x += fmaxf(mx, 0.f);
                acc.y += fmaxf(my, 0.f);
                acc.z += fmaxf(mz, 0.f);
                acc.w += fmaxf(mw, 0.f);
            }
        }
    }
    out4[(size_t)n * 32 + f4] = acc;
}

// ---------------- launch ----------------
extern "C" void kernel_launch(void* const* d_in, const int* in_sizes, int n_in,
                              void* d_out, int out_size, void* d_ws, size_t ws_size,
                              hipStream_t stream) {
    const float* x      = (const float*)d_in[0];
    const int*   ei     = (const int*)d_in[1];
    const int*   ea     = (const int*)d_in[2];
    const float* aeW1   = (const float*)d_in[3];
    const float* aeb1   = (const float*)d_in[4];
    const float* aeg1   = (const float*)d_in[5];
    const float* aebe1  = (const float*)d_in[6];
    const float* aem1   = (const float*)d_in[7];
    const float* aev1   = (const float*)d_in[8];
    const float* aeW2   = (const float*)d_in[9];
    const float* aeb2   = (const float*)d_in[10];
    const float* aeg2   = (const float*)d_in[11];
    const float* aebe2  = (const float*)d_in[12];
    const float* aem2   = (const float*)d_in[13];
    const float* aev2   = (const float*)d_in[14];
    const float* aeW3   = (const float*)d_in[15];
    const float* aeb3   = (const float*)d_in[16];
    const float* bond   = (const float*)d_in[17];
    const float* eps    = (const float*)d_in[18];
    const float* mlpW1  = (const float*)d_in[19];
    const float* mlpb1  = (const float*)d_in[20];
    const float* mlpg   = (const float*)d_in[21];
    const float* mlpbe  = (const float*)d_in[22];
    const float* mlpm   = (const float*)d_in[23];
    const float* mlpv   = (const float*)d_in[24];
    const float* mlpW2  = (const float*)d_in[25];
    const float* mlpb2  = (const float*)d_in[26];
    const float* outg   = (const float*)d_in[27];
    const float* outbe  = (const float*)d_in[28];
    const float* outm   = (const float*)d_in[29];
    const float* outv   = (const float*)d_in[30];

    float* bufB = (float*)d_out;                       // N*D fp32 (also final output)
    char*  ws   = (char*)d_ws;
    float* bufA = (float*)ws;                          // N*D fp32 = 102,400,000 B
    int*   deg  = (int*)(ws + 102400000);              // N ints
    int*   elist= (int*)(ws + 103200000);              // N*MAXDEG ints = 25.6 MB

    // CSR build (packed edge records)
    k_zero<<<(NNODES + 255) / 256, 256, 0, stream>>>(deg, NNODES);
    k_fill_edges<<<(NEDGES + 255) / 256, 256, 0, stream>>>(ei, ea, deg, elist, NEDGES);

    // atom encoder
    k_ae1<<<NNODES / 2, 256, 0, stream>>>(x, aeW1, aeb1, aeg1, aebe1, aem1, aev1, bufA);
    dim3 gg(NNODES / 64);
    k_lin<<<gg, 256, 0, stream>>>(bufA, aeW2, aeb2, aeg2, aebe2, aem2, aev2, bufB, 1, 1);
    k_lin<<<gg, 256, 0, stream>>>(bufB, aeW3, aeb3, nullptr, nullptr, nullptr, nullptr, bufA, 0, 0);

    // GIN layers; h starts in bufA. Parity lands layer-4 output in bufB == d_out.
    float* hcur = bufA;
    float* hoth = bufB;
    for (int l = 0; l < NLAYERS; ++l) {
        k_agg<<<NNODES / 8, 256, 0, stream>>>((const float4*)hcur, bond, eps, l,
                                              deg, elist, (float4*)hoth);
        k_lin<<<gg, 256, 0, stream>>>(hoth, mlpW1 + (size_t)l * D * D, mlpb1 + (size_t)l * D,
                                      mlpg + (size_t)l * D, mlpbe + (size_t)l * D,
                                      mlpm + (size_t)l * D, mlpv + (size_t)l * D, hcur, 1, 1);
        k_lin<<<gg, 256, 0, stream>>>(hcur, mlpW2 + (size_t)l * D * D, mlpb2 + (size_t)l * D,
                                      outg + (size_t)l * D, outbe + (size_t)l * D,
                                      outm + (size_t)l * D, outv + (size_t)l * D, hoth,
                                      1, (l < NLAYERS - 1) ? 1 : 0);
        float* t = hcur; hcur = hoth; hoth = t;
    }
    (void)in_sizes; (void)n_in; (void)out_size; (void)ws_size;
}

// Round 3
// 809.195 us; speedup vs baseline: 3.8507x; 2.1631x over previous
//
#include <hip/hip_runtime.h>
#include <hip/hip_bf16.h>
#include <cstdint>
#include <cstddef>

#define D 128
#define NNODES 200000
#define NEDGES 500000
#define NLAYERS 5
#define BN_EPS 1e-5f
#define MAXDEG 24

typedef __attribute__((ext_vector_type(8))) short bf16x8;   // 8 bf16 in 4 VGPRs
typedef __attribute__((ext_vector_type(4))) float f32x4;    // MFMA accumulator

__device__ __forceinline__ unsigned short f2bf(float f) {
    union { float f; unsigned int u; } x; x.f = f;
    unsigned int r = (x.u + 0x7FFFu + ((x.u >> 16) & 1u)) >> 16;   // RNE
    return (unsigned short)r;
}

// ---------------- CSR build ----------------
__global__ void k_zero(int* __restrict__ p, int n) {
    int i = blockIdx.x * 256 + threadIdx.x;
    if (i < n) p[i] = 0;
}

// pack src (18 bits) + a0,a1,a2 (3 bits each) into one int per edge
__global__ void k_fill_edges(const int* __restrict__ ei, const int* __restrict__ ea,
                             int* __restrict__ deg, int* __restrict__ elist, int n_edges) {
    int e = blockIdx.x * 256 + threadIdx.x;
    if (e >= n_edges) return;
    int dst = ei[n_edges + e];
    int src = ei[e];
    int a0 = ea[e * 3], a1 = ea[e * 3 + 1], a2 = ea[e * 3 + 2];
    int rec = src | (a0 << 18) | (a1 << 21) | (a2 << 24);
    int pos = atomicAdd(&deg[dst], 1);
    if (pos < MAXDEG) elist[dst * MAXDEG + pos] = rec;
}

// ---------------- weight prep: fp32 [K][F] -> bf16 transposed [F][K] ----------------
// 12 matrices of 128x128: 0=aeW2, 1=aeW3, 2..6=mlpW1[l], 7..11=mlpW2[l]
__global__ void k_prep_w(const float* __restrict__ aeW2, const float* __restrict__ aeW3,
                         const float* __restrict__ mlpW1, const float* __restrict__ mlpW2,
                         unsigned short* __restrict__ wbt) {
    int m = blockIdx.x >> 3;                  // 0..11
    int s = (blockIdx.x & 7) * 256 + threadIdx.x;   // 0..2047
    int f = s >> 4;                           // 0..127
    int kc = (s & 15) * 8;                    // 0,8,...,120
    const float* W;
    if (m == 0) W = aeW2;
    else if (m == 1) W = aeW3;
    else if (m < 7) W = mlpW1 + (size_t)(m - 2) * D * D;
    else W = mlpW2 + (size_t)(m - 7) * D * D;
    unsigned short tmp[8];
#pragma unroll
    for (int j = 0; j < 8; ++j) tmp[j] = f2bf(W[(size_t)(kc + j) * D + f]);
    *(int4*)(wbt + (size_t)m * D * D + (size_t)f * D + kc) = *(int4*)tmp;
}

// ---------------- atom encoder layer 1 (persistent, BN folded) ----------------
__global__ void k_ae1(const float* __restrict__ x, const float* __restrict__ W,
                      const float* __restrict__ b, const float* __restrict__ g,
                      const float* __restrict__ be, const float* __restrict__ m,
                      const float* __restrict__ v, float* __restrict__ out) {
    __shared__ float sW[12][128];
    int tid = threadIdx.x;
    for (int i = tid; i < 12 * 128; i += 256) sW[i >> 7][i & 127] = W[i];
    int f0 = (tid & 31) * 4;
    int g8 = tid >> 5;
    float4 bb = *(const float4*)(b + f0);
    float4 gg = *(const float4*)(g + f0);
    float4 ee = *(const float4*)(be + f0);
    float4 mm = *(const float4*)(m + f0);
    float4 vv = *(const float4*)(v + f0);
    float A0 = gg.x * rsqrtf(vv.x + BN_EPS), S0 = (bb.x - mm.x) * A0 + ee.x;
    float A1 = gg.y * rsqrtf(vv.y + BN_EPS), S1 = (bb.y - mm.y) * A1 + ee.y;
    float A2 = gg.z * rsqrtf(vv.z + BN_EPS), S2 = (bb.z - mm.z) * A2 + ee.z;
    float A3 = gg.w * rsqrtf(vv.w + BN_EPS), S3 = (bb.w - mm.w) * A3 + ee.w;
    __syncthreads();
    for (int n = blockIdx.x * 8 + g8; n < NNODES; n += gridDim.x * 8) {
        const float4* xr = (const float4*)(x + (size_t)n * 12);
        float4 x0 = xr[0], x1 = xr[1], x2 = xr[2];
        float xv[12] = {x0.x, x0.y, x0.z, x0.w, x1.x, x1.y, x1.z, x1.w,
                        x2.x, x2.y, x2.z, x2.w};
        float a0 = 0.f, a1 = 0.f, a2 = 0.f, a3 = 0.f;
#pragma unroll
        for (int k = 0; k < 12; ++k) {
            float4 wv = *(float4*)&sW[k][f0];
            a0 += xv[k] * wv.x; a1 += xv[k] * wv.y;
            a2 += xv[k] * wv.z; a3 += xv[k] * wv.w;
        }
        float4 r;
        r.x = fmaxf(a0 * A0 + S0, 0.f);
        r.y = fmaxf(a1 * A1 + S1, 0.f);
        r.z = fmaxf(a2 * A2 + S2, 0.f);
        r.w = fmaxf(a3 * A3 + S3, 0.f);
        *(float4*)(out + (size_t)n * D + f0) = r;
    }
}

// ---------------- fused double GEMM via MFMA ----------------
// in fp32 [N][128] -> GEMM1(W1)+BN1+ReLU -> GEMM2(W2)+bias(+BN2)(+ReLU) -> out fp32
// 64-node tile, 256 threads (4 waves), K=128 fully in LDS, XOR-swizzled bf16 tiles.
#define SWZ(row, bytecol) (((row) * 256 + (bytecol)) ^ (((row) & 7) << 4))
__launch_bounds__(256, 2)
__global__ void k_mlp2(const float* __restrict__ in,
                       const unsigned short* __restrict__ W1t,  // bf16 [F][K]
                       const float* __restrict__ b1,
                       const float* __restrict__ g1, const float* __restrict__ be1,
                       const float* __restrict__ m1, const float* __restrict__ v1,
                       const unsigned short* __restrict__ W2t,  // bf16 [F][K]
                       const float* __restrict__ b2,
                       const float* __restrict__ g2, const float* __restrict__ be2,
                       const float* __restrict__ m2, const float* __restrict__ v2,
                       float* __restrict__ out, int do_bn2, int do_relu2) {
    __shared__ int4 sAq[1024];   // 16KB: A tile [64][128] bf16, swizzled
    __shared__ int4 sWq[2048];   // 32KB: W tile [128][128] bf16, swizzled
    __shared__ int4 sZq[1024];   // 16KB: z1 tile [64][128] bf16, swizzled
    char* sA = (char*)sAq;
    char* sW = (char*)sWq;
    char* sZ = (char*)sZq;
    int tid = threadIdx.x;
    size_t nb = (size_t)blockIdx.x * 64;

    // stage A: fp32 global -> bf16 LDS (swizzled)
#pragma unroll
    for (int i = 0; i < 8; ++i) {
        int s = tid + i * 256;               // 0..2047
        int n = s >> 5, f0 = (s & 31) * 4;
        float4 vv = *(const float4*)(in + (nb + n) * D + f0);
        unsigned short h[4] = {f2bf(vv.x), f2bf(vv.y), f2bf(vv.z), f2bf(vv.w)};
        *(uint2*)(sA + SWZ(n, f0 * 2)) = *(uint2*)h;
    }
    // stage W1 -> LDS; prefetch W2 -> regs
    int4 w2reg[8];
#pragma unroll
    for (int i = 0; i < 8; ++i) {
        int s = tid + i * 256;               // 0..2047 chunks of 16B
        int r = s >> 4, c = (s & 15) * 16;
        int4 wv = *(const int4*)((const char*)W1t + r * 256 + c);
        *(int4*)(sW + SWZ(r, c)) = wv;
        w2reg[i] = *(const int4*)((const char*)W2t + r * 256 + c);
    }
    __syncthreads();

    int lane = tid & 63;
    int w = tid >> 6;                        // wave id: cols [w*32, w*32+32)
    int arow = lane & 15;
    int kq = (lane >> 4) * 8;                // k sub-offset within 32-chunk

    // ---- GEMM1 ----
    f32x4 acc[4][2];
#pragma unroll
    for (int rt = 0; rt < 4; ++rt)
#pragma unroll
        for (int ct = 0; ct < 2; ++ct) acc[rt][ct] = (f32x4){0.f, 0.f, 0.f, 0.f};
#pragma unroll
    for (int kb = 0; kb < 4; ++kb) {
        int k0 = kb * 32 + kq;
        bf16x8 a[4], bf[2];
#pragma unroll
        for (int rt = 0; rt < 4; ++rt) {
            int row = rt * 16 + arow;
            a[rt] = *(bf16x8*)(sA + SWZ(row, k0 * 2));
        }
#pragma unroll
        for (int ct = 0; ct < 2; ++ct) {
            int row = w * 32 + ct * 16 + arow;
            bf[ct] = *(bf16x8*)(sW + SWZ(row, k0 * 2));
        }
#pragma unroll
        for (int rt = 0; rt < 4; ++rt)
#pragma unroll
            for (int ct = 0; ct < 2; ++ct)
                acc[rt][ct] = __builtin_amdgcn_mfma_f32_16x16x32_bf16(a[rt], bf[ct], acc[rt][ct], 0, 0, 0);
    }
    // epilogue1: bias+BN+ReLU (folded) -> bf16 -> sZ
#pragma unroll
    for (int ct = 0; ct < 2; ++ct) {
        int c = w * 32 + ct * 16 + arow;
        float sc = g1[c] * rsqrtf(v1[c] + BN_EPS);
        float sh = (b1[c] - m1[c]) * sc + be1[c];
#pragma unroll
        for (int rt = 0; rt < 4; ++rt) {
#pragma unroll
            for (int r = 0; r < 4; ++r) {
                int row = rt * 16 + (lane >> 4) * 4 + r;
                float z = fmaxf(acc[rt][ct][r] * sc + sh, 0.f);
                *(unsigned short*)(sZ + SWZ(row, c * 2)) = f2bf(z);
            }
        }
    }
    __syncthreads();
    // stage W2 from regs
#pragma unroll
    for (int i = 0; i < 8; ++i) {
        int s = tid + i * 256;
        int r = s >> 4, c = (s & 15) * 16;
        *(int4*)(sW + SWZ(r, c)) = w2reg[i];
    }
    __syncthreads();

    // ---- GEMM2 ----
#pragma unroll
    for (int rt = 0; rt < 4; ++rt)
#pragma unroll
        for (int ct = 0; ct < 2; ++ct) acc[rt][ct] = (f32x4){0.f, 0.f, 0.f, 0.f};
#pragma unroll
    for (int kb = 0; kb < 4; ++kb) {
        int k0 = kb * 32 + kq;
        bf16x8 a[4], bf[2];
#pragma unroll
        for (int rt = 0; rt < 4; ++rt) {
            int row = rt * 16 + arow;
            a[rt] = *(bf16x8*)(sZ + SWZ(row, k0 * 2));
        }
#pragma unroll
        for (int ct = 0; ct < 2; ++ct) {
            int row = w * 32 + ct * 16 + arow;
            bf[ct] = *(bf16x8*)(sW + SWZ(row, k0 * 2));
        }
#pragma unroll
        for (int rt = 0; rt < 4; ++rt)
#pragma unroll
            for (int ct = 0; ct < 2; ++ct)
                acc[rt][ct] = __builtin_amdgcn_mfma_f32_16x16x32_bf16(a[rt], bf[ct], acc[rt][ct], 0, 0, 0);
    }
    // epilogue2: bias (+BN2)(+ReLU) -> global fp32
#pragma unroll
    for (int ct = 0; ct < 2; ++ct) {
        int c = w * 32 + ct * 16 + arow;
        float sc = 1.f, sh;
        if (do_bn2) {
            sc = g2[c] * rsqrtf(v2[c] + BN_EPS);
            sh = (b2[c] - m2[c]) * sc + be2[c];
        } else {
            sh = b2[c];
        }
#pragma unroll
        for (int rt = 0; rt < 4; ++rt) {
#pragma unroll
            for (int r = 0; r < 4; ++r) {
                int row = rt * 16 + (lane >> 4) * 4 + r;
                float z = acc[rt][ct][r] * sc + sh;
                if (do_relu2) z = fmaxf(z, 0.f);
                out[(nb + row) * D + c] = z;
            }
        }
    }
}

// ---------------- GIN aggregate (fp32): z = (1+eps)*h + sum_in relu(h[src]+e_emb) ----------------
__global__ void k_agg(const float4* __restrict__ h4, const float* __restrict__ bond,
                      const float* __restrict__ eps_arr, int layer,
                      const int* __restrict__ deg, const int* __restrict__ elist,
                      float4* __restrict__ out4) {
    __shared__ float4 sB[24 * 32];
    int tid = threadIdx.x;
    const float4* bl = (const float4*)(bond + (size_t)layer * 3 * 8 * 128);
    for (int i = tid; i < 24 * 32; i += 256) sB[i] = bl[i];
    __syncthreads();
    int f4 = tid & 31;
    int n = blockIdx.x * 8 + (tid >> 5);
    float epsv = 1.f + eps_arr[layer];
    float4 hs = h4[(size_t)n * 32 + f4];
    float4 acc = make_float4(epsv * hs.x, epsv * hs.y, epsv * hs.z, epsv * hs.w);
    int dgr = min(deg[n], MAXDEG);
    int recv = (f4 < MAXDEG) ? elist[(size_t)n * MAXDEG + f4] : 0;
    for (int base = 0; base < dgr; base += 4) {
        float4 hv[4]; int rr[4];
#pragma unroll
        for (int j = 0; j < 4; ++j) {
            rr[j] = __shfl(recv, base + j, 32);
            if (base + j < dgr) hv[j] = h4[(size_t)(rr[j] & 0x3FFFF) * 32 + f4];
        }
#pragma unroll
        for (int j = 0; j < 4; ++j) {
            if (base + j < dgr) {
                int r = rr[j];
                float4 b0 = sB[((r >> 18) & 7) * 32 + f4];
                float4 b1 = sB[(8 + ((r >> 21) & 7)) * 32 + f4];
                float4 b2 = sB[(16 + ((r >> 24) & 7)) * 32 + f4];
                acc.x += fmaxf(hv[j].x + b0.x + b1.x + b2.x, 0.f);
                acc.y += fmaxf(hv[j].y + b0.y + b1.y + b2.y, 0.f);
                acc.z += fmaxf(hv[j].z + b0.z + b1.z + b2.z, 0.f);
                acc.w += fmaxf(hv[j].w + b0.w + b1.w + b2.w, 0.f);
            }
        }
    }
    out4[(size_t)n * 32 + f4] = acc;
}

// ---------------- launch ----------------
extern "C" void kernel_launch(void* const* d_in, const int* in_sizes, int n_in,
                              void* d_out, int out_size, void* d_ws, size_t ws_size,
                              hipStream_t stream) {
    const float* x      = (const float*)d_in[0];
    const int*   ei     = (const int*)d_in[1];
    const int*   ea     = (const int*)d_in[2];
    const float* aeW1   = (const float*)d_in[3];
    const float* aeb1   = (const float*)d_in[4];
    const float* aeg1   = (const float*)d_in[5];
    const float* aebe1  = (const float*)d_in[6];
    const float* aem1   = (const float*)d_in[7];
    const float* aev1   = (const float*)d_in[8];
    const float* aeW2   = (const float*)d_in[9];
    const float* aeb2   = (const float*)d_in[10];
    const float* aeg2   = (const float*)d_in[11];
    const float* aebe2  = (const float*)d_in[12];
    const float* aem2   = (const float*)d_in[13];
    const float* aev2   = (const float*)d_in[14];
    const float* aeW3   = (const float*)d_in[15];
    const float* aeb3   = (const float*)d_in[16];
    const float* bond   = (const float*)d_in[17];
    const float* eps    = (const float*)d_in[18];
    const float* mlpW1  = (const float*)d_in[19];
    const float* mlpb1  = (const float*)d_in[20];
    const float* mlpg   = (const float*)d_in[21];
    const float* mlpbe  = (const float*)d_in[22];
    const float* mlpm   = (const float*)d_in[23];
    const float* mlpv   = (const float*)d_in[24];
    const float* mlpW2  = (const float*)d_in[25];
    const float* mlpb2  = (const float*)d_in[26];
    const float* outg   = (const float*)d_in[27];
    const float* outbe  = (const float*)d_in[28];
    const float* outm   = (const float*)d_in[29];
    const float* outv   = (const float*)d_in[30];

    float* bufB = (float*)d_out;                  // h lives here after each layer
    char*  ws   = (char*)d_ws;
    float* bufA = (float*)ws;                     // 102,400,000 B
    int*   deg  = (int*)(ws + 102400000);         // 800,000 B
    int*   elist= (int*)(ws + 103200000);         // N*24*4 = 19,200,000 B
    unsigned short* wbt = (unsigned short*)(ws + 122400000);  // 12*128*128*2 = 393,216 B

    // CSR build + weight prep
    k_zero<<<(NNODES + 255) / 256, 256, 0, stream>>>(deg, NNODES);
    k_fill_edges<<<(NEDGES + 255) / 256, 256, 0, stream>>>(ei, ea, deg, elist, NEDGES);
    k_prep_w<<<96, 256, 0, stream>>>(aeW2, aeW3, mlpW1, mlpW2, wbt);

    // atom encoder: ae1 (x -> bufA), fused ae2+ae3 (bufA -> bufB)
    k_ae1<<<1280, 256, 0, stream>>>(x, aeW1, aeb1, aeg1, aebe1, aem1, aev1, bufA);
    k_mlp2<<<NNODES / 64, 256, 0, stream>>>(bufA,
        wbt + 0 * 16384, aeb2, aeg2, aebe2, aem2, aev2,
        wbt + 1 * 16384, aeb3, aeb3, aeb3, aeb3, aeb3,
        bufB, 0, 0);

    // GIN layers: agg (bufB -> bufA), fused MLP (bufA -> bufB)
    for (int l = 0; l < NLAYERS; ++l) {
        k_agg<<<NNODES / 8, 256, 0, stream>>>((const float4*)bufB, bond, eps, l,
                                              deg, elist, (float4*)bufA);
        k_mlp2<<<NNODES / 64, 256, 0, stream>>>(bufA,
            wbt + (size_t)(2 + l) * 16384, mlpb1 + (size_t)l * D,
            mlpg + (size_t)l * D, mlpbe + (size_t)l * D,
            mlpm + (size_t)l * D, mlpv + (size_t)l * D,
            wbt + (size_t)(7 + l) * 16384, mlpb2 + (size_t)l * D,
            outg + (size_t)l * D, outbe + (size_t)l * D,
            outm + (size_t)l * D, outv + (size_t)l * D,
            bufB, 1, (l < NLAYERS - 1) ? 1 : 0);
    }
    (void)in_sizes; (void)n_in; (void)out_size; (void)ws_size;
}